// Round 1
// baseline (305.348 us; speedup 1.0000x reference)
//
#include <hip/hip_runtime.h>

#define FEAT_H 64
#define FEAT_W 100
#define NANCH 9
#define NTOT (FEAT_H * FEAT_W * NANCH) /* 57600 */
#define NPAD 65536
#define PRE_NMS 6000
#define POST_NMS 300
#define NWORDS 94 /* ceil(6000/64) */
#define CH_STRIDE (FEAT_H * FEAT_W) /* 6400 */

typedef unsigned long long u64;
typedef unsigned int u32;

// Base anchors (ratios 0.5,1,2 x scales 8,16,32), precomputed exactly as
// numpy's _base_anchors (banker's rounding on 11.5 -> 12).
__constant__ double c_base[9][4] = {
    {-84.0, -40.0, 99.0, 55.0},    {-176.0, -88.0, 191.0, 103.0},
    {-360.0, -184.0, 375.0, 199.0},{-56.0, -56.0, 71.0, 71.0},
    {-120.0, -120.0, 135.0, 135.0},{-248.0, -248.0, 263.0, 263.0},
    {-36.0, -80.0, 51.0, 95.0},    {-80.0, -168.0, 95.0, 183.0},
    {-168.0, -344.0, 183.0, 359.0}};

struct BoxD { double x1, y1, x2, y2; };

__device__ __forceinline__ BoxD decode_box(int i, const float* __restrict__ bbox,
                                           double imw1, double imh1) {
  int pos = i / NANCH;
  int a = i - pos * NANCH;
  int h = pos / FEAT_W;
  int w = pos - h * FEAT_W;
  double ax1 = c_base[a][0] + 16.0 * (double)w;
  double ay1 = c_base[a][1] + 16.0 * (double)h;
  double ax2 = c_base[a][2] + 16.0 * (double)w;
  double ay2 = c_base[a][3] + 16.0 * (double)h;
  double wd = ax2 - ax1 + 1.0;
  double hg = ay2 - ay1 + 1.0;
  double cx = ax1 + 0.5 * wd;
  double cy = ay1 + 0.5 * hg;
  const float* bp = bbox + (size_t)(4 * a) * CH_STRIDE + pos;
  double dx = (double)bp[0];
  double dy = (double)bp[CH_STRIDE];
  double dw = (double)bp[2 * CH_STRIDE];
  double dh = (double)bp[3 * CH_STRIDE];
  double pcx = dx * wd + cx;
  double pcy = dy * hg + cy;
  double pw = exp(dw) * wd;
  double ph = exp(dh) * hg;
  BoxD b;
  b.x1 = fmin(fmax(pcx - 0.5 * pw, 0.0), imw1);
  b.y1 = fmin(fmax(pcy - 0.5 * ph, 0.0), imh1);
  b.x2 = fmin(fmax(pcx + 0.5 * pw, 0.0), imw1);
  b.y2 = fmin(fmax(pcy + 0.5 * ph, 0.0), imh1);
  return b;
}

// score + validity -> sortable 64-bit key (descending score, index-asc tiebreak
// handled by separate val array in the sort comparator)
__global__ void k_score(const float* __restrict__ cls, const float* __restrict__ bbox,
                        const int* __restrict__ imh, const int* __restrict__ imw,
                        u64* __restrict__ keys, u32* __restrict__ vals) {
  int i = blockIdx.x * blockDim.x + threadIdx.x;
  if (i >= NPAD) return;
  if (i >= NTOT) { keys[i] = 0ULL; vals[i] = 0xFFFFFFFFu; return; }
  double imh1 = (double)(imh[0] - 1);
  double imw1 = (double)(imw[0] - 1);
  BoxD b = decode_box(i, bbox, imw1, imh1);
  bool valid = (b.x2 - b.x1 + 1.0 >= 16.0) && (b.y2 - b.y1 + 1.0 >= 16.0);
  int pos = i / NANCH;
  int a = i - pos * NANCH;
  double c0 = (double)cls[(size_t)(2 * a) * CH_STRIDE + pos];
  double c1 = (double)cls[(size_t)(2 * a + 1) * CH_STRIDE + pos];
  double m = fmax(c0, c1);
  double e0 = exp(c0 - m), e1 = exp(c1 - m);
  double s = e1 / (e0 + e1);
  double masked = valid ? s : (double)(-1e30f);
  u64 u = (u64)__double_as_longlong(masked);
  u = (u >> 63) ? ~u : (u | 0x8000000000000000ULL);
  keys[i] = u;
  vals[i] = (u32)i;
}

// comparator: does (ka,va) come AFTER (kb,vb) in desired order (score desc, idx asc)?
__device__ __forceinline__ bool comes_after(u64 ka, u32 va, u64 kb, u32 vb) {
  return (ka < kb) || (ka == kb && va > vb);
}

__global__ __launch_bounds__(1024) void k_sort_local(u64* keys, u32* vals) {
  __shared__ u64 sk[2048];
  __shared__ u32 sv[2048];
  int base = blockIdx.x * 2048;
  for (int t = threadIdx.x; t < 2048; t += 1024) { sk[t] = keys[base + t]; sv[t] = vals[base + t]; }
  __syncthreads();
  for (int k = 2; k <= 2048; k <<= 1) {
    for (int j = k >> 1; j > 0; j >>= 1) {
      int t = threadIdx.x;
      int i = ((t & ~(j - 1)) << 1) | (t & (j - 1));
      int l = i | j;
      bool up = (((base + i) & k) == 0);
      u64 ka = sk[i], kb = sk[l];
      u32 va = sv[i], vb = sv[l];
      if (comes_after(ka, va, kb, vb) == up) { sk[i] = kb; sv[i] = vb; sk[l] = ka; sv[l] = va; }
      __syncthreads();
    }
  }
  for (int t = threadIdx.x; t < 2048; t += 1024) { keys[base + t] = sk[t]; vals[base + t] = sv[t]; }
}

__global__ void k_sort_global(u64* keys, u32* vals, int j, int k) {
  int i = blockIdx.x * blockDim.x + threadIdx.x;
  int l = i ^ j;
  if (l <= i || i >= NPAD) return;
  u64 ka = keys[i], kb = keys[l];
  u32 va = vals[i], vb = vals[l];
  bool up = ((i & k) == 0);
  if (comes_after(ka, va, kb, vb) == up) { keys[i] = kb; vals[i] = vb; keys[l] = ka; vals[l] = va; }
}

__global__ __launch_bounds__(1024) void k_sort_local_merge(u64* keys, u32* vals, int k) {
  __shared__ u64 sk[2048];
  __shared__ u32 sv[2048];
  int base = blockIdx.x * 2048;
  for (int t = threadIdx.x; t < 2048; t += 1024) { sk[t] = keys[base + t]; sv[t] = vals[base + t]; }
  __syncthreads();
  for (int j = 1024; j > 0; j >>= 1) {
    int t = threadIdx.x;
    int i = ((t & ~(j - 1)) << 1) | (t & (j - 1));
    int l = i | j;
    bool up = (((base + i) & k) == 0);
    u64 ka = sk[i], kb = sk[l];
    u32 va = sv[i], vb = sv[l];
    if (comes_after(ka, va, kb, vb) == up) { sk[i] = kb; sv[i] = vb; sk[l] = ka; sv[l] = va; }
    __syncthreads();
  }
  for (int t = threadIdx.x; t < 2048; t += 1024) { keys[base + t] = sk[t]; vals[base + t] = sv[t]; }
}

__global__ void k_gather(const u32* __restrict__ vals, const float* __restrict__ bbox,
                         const int* __restrict__ imh, const int* __restrict__ imw,
                         double4* __restrict__ sboxes) {
  int r = blockIdx.x * blockDim.x + threadIdx.x;
  if (r >= PRE_NMS) return;
  double imh1 = (double)(imh[0] - 1);
  double imw1 = (double)(imw[0] - 1);
  int i = (int)vals[r];
  BoxD b = decode_box(i, bbox, imw1, imh1);
  sboxes[r] = make_double4(b.x1, b.y1, b.x2, b.y2);
}

__global__ void k_mask(const double4* __restrict__ sboxes, u64* __restrict__ mask) {
  __shared__ double4 cb[64];
  int bc = blockIdx.x, br = blockIdx.y;
  int t = threadIdx.x;
  int j0 = bc * 64;
  int jt = j0 + t;
  cb[t] = (jt < PRE_NMS) ? sboxes[jt] : make_double4(0.0, 0.0, 0.0, 0.0);
  __syncthreads();
  int i = br * 64 + t;
  if (i >= PRE_NMS) return;
  double4 rb = sboxes[i];
  double areai = (rb.z - rb.x) * (rb.w - rb.y);
  u64 bits = 0;
  int cmax = min(64, PRE_NMS - j0);
  for (int c = 0; c < cmax; ++c) {
    int j = j0 + c;
    if (j <= i) continue;
    double4 cbx = cb[c];
    double xx1 = fmax(rb.x, cbx.x), yy1 = fmax(rb.y, cbx.y);
    double xx2 = fmin(rb.z, cbx.z), yy2 = fmin(rb.w, cbx.w);
    double w = fmax(xx2 - xx1, 0.0), h = fmax(yy2 - yy1, 0.0);
    double inter = w * h;
    double areaj = (cbx.z - cbx.x) * (cbx.w - cbx.y);
    double iou = inter / (areai + areaj - inter);
    if (iou > 0.7) bits |= (1ULL << c);
  }
  mask[(size_t)i * NWORDS + bc] = bits;
}

// Single-wave greedy scan; suppression bitmap lives in 2 VGPRs/lane (94 words
// across 64 lanes). Early exit at 300 kept (reference truncates to 300).
__global__ void k_scan(const u64* __restrict__ mask, int* __restrict__ keep) {
  int lane = threadIdx.x; // 64 threads = 1 wave
  for (int r = lane; r < POST_NMS; r += 64) keep[r] = 0; // nonzero fill_value=0
  u64 rem0 = 0, rem1 = 0;
  int nkeep = 0;
  for (int i = 0; i < PRE_NMS; ++i) {
    int wd = i >> 6;
    u64 w0 = __shfl(rem0, wd & 63);
    u64 w1 = __shfl(rem1, (wd >= 64) ? (wd - 64) : 0);
    u64 word = (wd < 64) ? w0 : w1;
    if (!((word >> (i & 63)) & 1ULL)) {
      if (lane == 0) keep[nkeep] = i;
      ++nkeep;
      if (nkeep >= POST_NMS) break;
      const u64* row = mask + (size_t)i * NWORDS;
      rem0 |= row[lane];
      if (lane < NWORDS - 64) rem1 |= row[64 + lane];
    }
  }
}

__global__ void k_out(const double4* __restrict__ sboxes, const int* __restrict__ keep,
                      float* __restrict__ out) {
  int r = blockIdx.x * blockDim.x + threadIdx.x;
  if (r >= POST_NMS) return;
  int kk = keep[r];
  double4 b = sboxes[kk];
  float* o = out + r * 5;
  o[0] = 0.0f;
  o[1] = (float)b.x;
  o[2] = (float)b.y;
  o[3] = (float)b.z;
  o[4] = (float)b.w;
}

extern "C" void kernel_launch(void* const* d_in, const int* in_sizes, int n_in,
                              void* d_out, int out_size, void* d_ws, size_t ws_size,
                              hipStream_t stream) {
  const float* cls = (const float*)d_in[0];
  const float* bbox = (const float*)d_in[1];
  const int* imh = (const int*)d_in[2];
  const int* imw = (const int*)d_in[3];
  float* out = (float*)d_out;

  // Workspace layout (keys/vals lifetime ends before mask is written -> overlay):
  // [0, 192512)            sboxes   (6016 * sizeof(double4))
  // [192512, 194560)       keep     (300 ints, padded)
  // [194560, ...)          mask     (6000*94*8 = 4512000)  OVERLAYS keys/vals
  //   keys = 194560 .. +524288 ; vals = +524288 .. +786432
  char* p = (char*)d_ws;
  double4* sboxes = (double4*)p;
  int* keep = (int*)(p + 192512);
  u64* mask = (u64*)(p + 194560);
  u64* keys = (u64*)(p + 194560);
  u32* vals = (u32*)(p + 194560 + (size_t)NPAD * 8);

  k_score<<<NPAD / 256, 256, 0, stream>>>(cls, bbox, imh, imw, keys, vals);

  // Bitonic sort of 65536 (key,val) pairs: local sort (k<=2048 in LDS), then
  // for each phase k: global stages j>=2048, LDS merge for j<=1024.
  k_sort_local<<<32, 1024, 0, stream>>>(keys, vals);
  for (int k = 4096; k <= 65536; k <<= 1) {
    for (int j = k >> 1; j >= 2048; j >>= 1)
      k_sort_global<<<NPAD / 256, 256, 0, stream>>>(keys, vals, j, k);
    k_sort_local_merge<<<32, 1024, 0, stream>>>(keys, vals, k);
  }

  k_gather<<<(PRE_NMS + 255) / 256, 256, 0, stream>>>(vals, bbox, imh, imw, sboxes);
  k_mask<<<dim3(NWORDS, NWORDS), 64, 0, stream>>>(sboxes, mask);
  k_scan<<<1, 64, 0, stream>>>(mask, keep);
  k_out<<<(POST_NMS + 63) / 64, 64, 0, stream>>>(sboxes, keep, out);
}

// Round 2
// 235.247 us; speedup vs baseline: 1.2980x; 1.2980x over previous
//
#include <hip/hip_runtime.h>

#define FEAT_H 64
#define FEAT_W 100
#define NANCH 9
#define NTOT (FEAT_H * FEAT_W * NANCH) /* 57600 */
#define NPAD 65536
#define PRE_NMS 6000
#define POST_NMS 300
#define NWORDS 94 /* ceil(6000/64) */
#define CH_STRIDE (FEAT_H * FEAT_W) /* 6400 */
#define RING 64 /* prefetch ring rows (48KB LDS) */

typedef unsigned long long u64;
typedef unsigned int u32;

__constant__ double c_base[9][4] = {
    {-84.0, -40.0, 99.0, 55.0},    {-176.0, -88.0, 191.0, 103.0},
    {-360.0, -184.0, 375.0, 199.0},{-56.0, -56.0, 71.0, 71.0},
    {-120.0, -120.0, 135.0, 135.0},{-248.0, -248.0, 263.0, 263.0},
    {-36.0, -80.0, 51.0, 95.0},    {-80.0, -168.0, 95.0, 183.0},
    {-168.0, -344.0, 183.0, 359.0}};

struct BoxD { double x1, y1, x2, y2; };

__device__ __forceinline__ BoxD decode_box(int i, const float* __restrict__ bbox,
                                           double imw1, double imh1) {
  int pos = i / NANCH;
  int a = i - pos * NANCH;
  int h = pos / FEAT_W;
  int w = pos - h * FEAT_W;
  double ax1 = c_base[a][0] + 16.0 * (double)w;
  double ay1 = c_base[a][1] + 16.0 * (double)h;
  double ax2 = c_base[a][2] + 16.0 * (double)w;
  double ay2 = c_base[a][3] + 16.0 * (double)h;
  double wd = ax2 - ax1 + 1.0;
  double hg = ay2 - ay1 + 1.0;
  double cx = ax1 + 0.5 * wd;
  double cy = ay1 + 0.5 * hg;
  const float* bp = bbox + (size_t)(4 * a) * CH_STRIDE + pos;
  double dx = (double)bp[0];
  double dy = (double)bp[CH_STRIDE];
  double dw = (double)bp[2 * CH_STRIDE];
  double dh = (double)bp[3 * CH_STRIDE];
  double pcx = dx * wd + cx;
  double pcy = dy * hg + cy;
  double pw = exp(dw) * wd;
  double ph = exp(dh) * hg;
  BoxD b;
  b.x1 = fmin(fmax(pcx - 0.5 * pw, 0.0), imw1);
  b.y1 = fmin(fmax(pcy - 0.5 * ph, 0.0), imh1);
  b.x2 = fmin(fmax(pcx + 0.5 * pw, 0.0), imw1);
  b.y2 = fmin(fmax(pcy + 0.5 * ph, 0.0), imh1);
  return b;
}

__device__ __forceinline__ u64 score_key(int i, const float* __restrict__ cls,
                                         const float* __restrict__ bbox,
                                         double imw1, double imh1) {
  BoxD b = decode_box(i, bbox, imw1, imh1);
  bool valid = (b.x2 - b.x1 + 1.0 >= 16.0) && (b.y2 - b.y1 + 1.0 >= 16.0);
  int pos = i / NANCH;
  int a = i - pos * NANCH;
  double c0 = (double)cls[(size_t)(2 * a) * CH_STRIDE + pos];
  double c1 = (double)cls[(size_t)(2 * a + 1) * CH_STRIDE + pos];
  double m = fmax(c0, c1);
  double e0 = exp(c0 - m), e1 = exp(c1 - m);
  double s = e1 / (e0 + e1);
  double masked = valid ? s : (double)(-1e30f);
  u64 u = (u64)__double_as_longlong(masked);
  return (u >> 63) ? ~u : (u | 0x8000000000000000ULL);
}

// order comparators: "before" = comes earlier in output (score desc, idx asc)
__device__ __forceinline__ bool before(u64 ka, u32 va, u64 kb, u32 vb) {
  return (ka > kb) || (ka == kb && va < vb);
}
__device__ __forceinline__ bool comes_after(u64 ka, u32 va, u64 kb, u32 vb) {
  return (ka < kb) || (ka == kb && va > vb);
}

// Fused: compute 2048 keys per block, bitonic-sort them descending in LDS,
// write sorted chunk. 32 blocks cover NPAD=65536 (pads key=0 sink to tail).
__global__ __launch_bounds__(1024) void k_score_sort(
    const float* __restrict__ cls, const float* __restrict__ bbox,
    const int* __restrict__ imh, const int* __restrict__ imw,
    u64* __restrict__ keys, u32* __restrict__ vals) {
  __shared__ u64 sk[2048];
  __shared__ u32 sv[2048];
  int base = blockIdx.x * 2048;
  double imh1 = (double)(imh[0] - 1);
  double imw1 = (double)(imw[0] - 1);
  for (int t = threadIdx.x; t < 2048; t += 1024) {
    int i = base + t;
    if (i < NTOT) { sk[t] = score_key(i, cls, bbox, imw1, imh1); sv[t] = (u32)i; }
    else { sk[t] = 0ULL; sv[t] = (u32)i; }
  }
  __syncthreads();
  for (int k = 2; k <= 2048; k <<= 1) {
    for (int j = k >> 1; j > 0; j >>= 1) {
      int t = threadIdx.x;
      int i = ((t & ~(j - 1)) << 1) | (t & (j - 1));
      int l = i | j;
      bool up = ((i & k) == 0);
      u64 ka = sk[i], kb = sk[l];
      u32 va = sv[i], vb = sv[l];
      if (comes_after(ka, va, kb, vb) == up) { sk[i] = kb; sv[i] = vb; sk[l] = ka; sv[l] = va; }
      __syncthreads();
    }
  }
  for (int t = threadIdx.x; t < 2048; t += 1024) { keys[base + t] = sk[t]; vals[base + t] = sv[t]; }
}

// Merge-path: merge nPairs pairs of sorted lists (each inLen) into lists of
// outLen (truncated prefix of the merge). If sboxes != nullptr (final level),
// decode boxes for the top outLen instead of writing keys/vals.
__global__ void k_merge(const u64* __restrict__ ik, const u32* __restrict__ iv,
                        u64* __restrict__ ok, u32* __restrict__ ov,
                        int inLen, int outLen, int nPairs,
                        const float* __restrict__ bbox, const int* __restrict__ imh,
                        const int* __restrict__ imw, double4* __restrict__ sboxes) {
  int p0 = blockIdx.x * blockDim.x + threadIdx.x;
  if (p0 >= nPairs * outLen) return;
  int pair = p0 / outLen;
  int p = p0 - pair * outLen;
  const u64* Ak = ik + (size_t)pair * 2 * inLen;
  const u32* Av = iv + (size_t)pair * 2 * inLen;
  const u64* Bk = Ak + inLen;
  const u32* Bv = Av + inLen;
  int La = inLen, Lb = inLen;
  int lo = max(0, p - Lb), hi = min(p, La);
  while (lo < hi) {
    int a = (lo + hi) >> 1;
    int b = p - a - 1;
    if (before(Bk[b], Bv[b], Ak[a], Av[a])) hi = a; else lo = a + 1;
  }
  int a = lo, b = p - a;
  bool takeA = (a < La) && (b >= Lb || !before(Bk[b], Bv[b], Ak[a], Av[a]));
  u64 kk = takeA ? Ak[a] : Bk[b];
  u32 vv = takeA ? Av[a] : Bv[b];
  if (sboxes) {
    double imh1 = (double)(imh[0] - 1);
    double imw1 = (double)(imw[0] - 1);
    BoxD bx = decode_box((int)vv, bbox, imw1, imh1);
    sboxes[p] = make_double4(bx.x1, bx.y1, bx.x2, bx.y2);
  } else {
    ok[(size_t)pair * outLen + p] = kk;
    ov[(size_t)pair * outLen + p] = vv;
  }
}

__global__ void k_mask(const double4* __restrict__ sboxes, u64* __restrict__ mask) {
  __shared__ double4 cb[64];
  int bc = blockIdx.x, br = blockIdx.y;
  int t = threadIdx.x;
  int j0 = bc * 64;
  int jt = j0 + t;
  cb[t] = (jt < PRE_NMS) ? sboxes[jt] : make_double4(0.0, 0.0, 0.0, 0.0);
  __syncthreads();
  int i = br * 64 + t;
  if (i >= PRE_NMS) return;
  double4 rb = sboxes[i];
  double areai = (rb.z - rb.x) * (rb.w - rb.y);
  u64 bits = 0;
  int cmax = min(64, PRE_NMS - j0);
  for (int c = 0; c < cmax; ++c) {
    int j = j0 + c;
    if (j <= i) continue;
    double4 cbx = cb[c];
    double xx1 = fmax(rb.x, cbx.x), yy1 = fmax(rb.y, cbx.y);
    double xx2 = fmin(rb.z, cbx.z), yy2 = fmin(rb.w, cbx.w);
    double w = fmax(xx2 - xx1, 0.0), h = fmax(yy2 - yy1, 0.0);
    double inter = w * h;
    double areaj = (cbx.z - cbx.x) * (cbx.w - cbx.y);
    double iou = inter / (areai + areaj - inter);
    if (iou > 0.7) bits |= (1ULL << c);
  }
  mask[(size_t)i * NWORDS + bc] = bits;
}

// Producer/consumer scan: wave 0 does the greedy NMS scan; waves 1..7 prefetch
// mask rows into a RING-row LDS ring buffer ahead of scan_pos. Epilogue writes
// the final (300,5) output.
__global__ __launch_bounds__(512) void k_scan(const u64* __restrict__ mask,
                                              const double4* __restrict__ sboxes,
                                              float* __restrict__ out) {
  __shared__ u64 ring[RING * NWORDS];
  __shared__ int ready[RING];
  __shared__ int keep_lds[POST_NMS];
  __shared__ int scan_pos, fetch_next, done;

  int tid = threadIdx.x;
  int lane = tid & 63;
  int wave = tid >> 6;
  for (int r = tid; r < POST_NMS; r += 512) keep_lds[r] = 0;
  for (int r = tid; r < RING; r += 512) ready[r] = 0;
  if (tid == 0) { scan_pos = 0; fetch_next = 0; done = 0; }
  __syncthreads();

  if (wave == 0) {
    // ---- scanner ----
    u64 rem0 = 0, rem1 = 0;
    int nkeep = 0;
    int i = 0;
    while (i < PRE_NMS && nkeep < POST_NMS) {
      if (lane == 0)
        __hip_atomic_store(&scan_pos, i, __ATOMIC_RELAXED, __HIP_MEMORY_SCOPE_WORKGROUP);
      int wd = i >> 6, bit = i & 63;
      u64 w0 = __shfl(rem0, wd & 63);
      u64 w1 = __shfl(rem1, (wd >= 64) ? (wd - 64) : 0);
      u64 w = (wd < 64) ? w0 : w1;
      u64 avail = ~w & (~0ULL << bit);
      if (wd == NWORDS - 1) avail &= ((1ULL << (PRE_NMS - (NWORDS - 1) * 64)) - 1);
      if (avail == 0) { i = (wd + 1) << 6; continue; }
      int b = __builtin_ctzll(avail);
      i = (wd << 6) + b;
      if (lane == 0) keep_lds[nkeep] = i;
      ++nkeep;
      if (nkeep >= POST_NMS) break;
      // consume row i from the ring
      int slot = i & (RING - 1);
      while (__hip_atomic_load(&ready[slot], __ATOMIC_ACQUIRE, __HIP_MEMORY_SCOPE_WORKGROUP) != i + 1) {}
      const u64* row = &ring[slot * NWORDS];
      rem0 |= row[lane];
      if (lane < NWORDS - 64) rem1 |= row[64 + lane];
      i += 1;
    }
    if (lane == 0)
      __hip_atomic_store(&done, 1, __ATOMIC_RELEASE, __HIP_MEMORY_SCOPE_WORKGROUP);
  } else {
    // ---- prefetchers (batch of 2 rows) ----
    for (;;) {
      int j0 = 0;
      if (lane == 0) j0 = atomicAdd(&fetch_next, 2);
      j0 = __shfl(j0, 0);
      if (j0 >= PRE_NMS) break;
      int jlast = min(j0 + 1, PRE_NMS - 1);
      bool exit_now = false;
      for (;;) {
        int sp = __hip_atomic_load(&scan_pos, __ATOMIC_RELAXED, __HIP_MEMORY_SCOPE_WORKGROUP);
        if (jlast < sp + RING) break;
        if (__hip_atomic_load(&done, __ATOMIC_ACQUIRE, __HIP_MEMORY_SCOPE_WORKGROUP)) { exit_now = true; break; }
        __builtin_amdgcn_s_sleep(8);
      }
      if (exit_now) break;
      const u64* r0 = mask + (size_t)j0 * NWORDS;
      u64 a0 = r0[lane];
      u64 a1 = (lane < NWORDS - 64) ? r0[64 + lane] : 0;
      u64 b0 = 0, b1 = 0;
      bool two = (j0 + 1 < PRE_NMS);
      if (two) {
        const u64* r1 = mask + (size_t)(j0 + 1) * NWORDS;
        b0 = r1[lane];
        b1 = (lane < NWORDS - 64) ? r1[64 + lane] : 0;
      }
      int s0 = j0 & (RING - 1);
      ring[s0 * NWORDS + lane] = a0;
      if (lane < NWORDS - 64) ring[s0 * NWORDS + 64 + lane] = a1;
      if (two) {
        int s1 = (j0 + 1) & (RING - 1);
        ring[s1 * NWORDS + lane] = b0;
        if (lane < NWORDS - 64) ring[s1 * NWORDS + 64 + lane] = b1;
      }
      __threadfence_block();
      if (lane == 0) {
        __hip_atomic_store(&ready[s0], j0 + 1, __ATOMIC_RELEASE, __HIP_MEMORY_SCOPE_WORKGROUP);
        if (two)
          __hip_atomic_store(&ready[(j0 + 1) & (RING - 1)], j0 + 2, __ATOMIC_RELEASE, __HIP_MEMORY_SCOPE_WORKGROUP);
      }
      if (__hip_atomic_load(&done, __ATOMIC_ACQUIRE, __HIP_MEMORY_SCOPE_WORKGROUP)) break;
    }
  }
  __syncthreads();
  // epilogue: write (300,5) output
  for (int r = tid; r < POST_NMS; r += 512) {
    int kk = keep_lds[r];
    double4 b = sboxes[kk];
    float* o = out + r * 5;
    o[0] = 0.0f;
    o[1] = (float)b.x;
    o[2] = (float)b.y;
    o[3] = (float)b.z;
    o[4] = (float)b.w;
  }
}

extern "C" void kernel_launch(void* const* d_in, const int* in_sizes, int n_in,
                              void* d_out, int out_size, void* d_ws, size_t ws_size,
                              hipStream_t stream) {
  const float* cls = (const float*)d_in[0];
  const float* bbox = (const float*)d_in[1];
  const int* imh = (const int*)d_in[2];
  const int* imw = (const int*)d_in[3];
  float* out = (float*)d_out;

  // Workspace:
  // [0, 192512)           sboxes (6016 double4)
  // [192512, 716800)      bufA keys (65536 u64)
  // [716800, 978944)      bufA vals (65536 u32)
  // [978944, 1503232)     bufB keys
  // [1503232, 1765376)    bufB vals
  // [192512, 4704512)     mask (6000*94 u64) — overlays bufA/bufB, written
  //                       only after the final merge has consumed bufA.
  char* p = (char*)d_ws;
  double4* sboxes = (double4*)p;
  u64* Ak = (u64*)(p + 192512);
  u32* Av = (u32*)(p + 716800);
  u64* Bk = (u64*)(p + 978944);
  u32* Bv = (u32*)(p + 1503232);
  u64* mask = (u64*)(p + 192512);

  k_score_sort<<<32, 1024, 0, stream>>>(cls, bbox, imh, imw, Ak, Av);
  // 32 lists x2048 -> 16 x4096 -> 8 x6144 -> 4 x6144 -> 2 x6144 -> top-6000
  k_merge<<<(16 * 4096 + 255) / 256, 256, 0, stream>>>(Ak, Av, Bk, Bv, 2048, 4096, 16,
                                                       bbox, imh, imw, nullptr);
  k_merge<<<(8 * 6144 + 255) / 256, 256, 0, stream>>>(Bk, Bv, Ak, Av, 4096, 6144, 8,
                                                      bbox, imh, imw, nullptr);
  k_merge<<<(4 * 6144 + 255) / 256, 256, 0, stream>>>(Ak, Av, Bk, Bv, 6144, 6144, 4,
                                                      bbox, imh, imw, nullptr);
  k_merge<<<(2 * 6144 + 255) / 256, 256, 0, stream>>>(Bk, Bv, Ak, Av, 6144, 6144, 2,
                                                      bbox, imh, imw, nullptr);
  k_merge<<<(PRE_NMS + 255) / 256, 256, 0, stream>>>(Ak, Av, nullptr, nullptr, 6144, PRE_NMS, 1,
                                                     bbox, imh, imw, sboxes);
  k_mask<<<dim3(NWORDS, NWORDS), 64, 0, stream>>>(sboxes, mask);
  k_scan<<<1, 512, 0, stream>>>(mask, sboxes, out);
}